// Round 1
// baseline (1381.152 us; speedup 1.0000x reference)
//
#include <hip/hip_runtime.h>
#include <hip/hip_bf16.h>
#include <math.h>

#define B_   4
#define S_   4096
#define D_   1024
#define MD_  512
#define NTOK (B_ * S_)      // 16384
#define CHUNK 128
#define NCH  (S_ / CHUNK)   // 32

__device__ __forceinline__ float gelu_f(float x) {
    // jax.nn.gelu default: tanh approximation
    float x3 = x * x * x;
    return 0.5f * x * (1.0f + tanhf(0.7978845608028654f * (x + 0.044715f * x3)));
}

__device__ __forceinline__ float gate_from_ff(const float* ff) {
    // gate = 1 - sigmoid(forget_factor)
    return 1.0f - 1.0f / (1.0f + expf(-ff[0]));
}

// -------- generic f32 GEMM: C[N,M] = epi((A [+A2]) @ W + bias) --------
// 64x64 tile, BK=16, 256 threads, 4x4 micro-tile per thread.
template<int EPI, int HB, int HA2>
__global__ __launch_bounds__(256) void gemm_f32_k(
    const float* __restrict__ A, const float* __restrict__ A2,
    const float* __restrict__ W, const float* __restrict__ bias,
    float* __restrict__ C, int N, int K, int M)
{
    __shared__ float As[16][64];   // [k][row]
    __shared__ float Bs[16][64];   // [k][col]
    const int tid = threadIdx.x;
    const int tx = tid & 15, ty = tid >> 4;
    const int rowBase = blockIdx.y * 64;
    const int colBase = blockIdx.x * 64;

    const int lr = tid >> 2, lk = (tid & 3) << 2;   // A-stage: row lr, k off lk
    const int wk = tid >> 4, wc = (tid & 15) << 2;  // W-stage: k row wk, col wc

    float acc[4][4];
#pragma unroll
    for (int i = 0; i < 4; ++i)
#pragma unroll
        for (int j = 0; j < 4; ++j) acc[i][j] = 0.f;

    for (int k0 = 0; k0 < K; k0 += 16) {
        float4 av = *(const float4*)(A + (size_t)(rowBase + lr) * K + k0 + lk);
        if (HA2) {
            float4 a2 = *(const float4*)(A2 + (size_t)(rowBase + lr) * K + k0 + lk);
            av.x += a2.x; av.y += a2.y; av.z += a2.z; av.w += a2.w;
        }
        float4 wv = *(const float4*)(W + (size_t)(k0 + wk) * M + colBase + wc);
        As[lk + 0][lr] = av.x; As[lk + 1][lr] = av.y;
        As[lk + 2][lr] = av.z; As[lk + 3][lr] = av.w;
        *(float4*)&Bs[wk][wc] = wv;
        __syncthreads();
#pragma unroll
        for (int k = 0; k < 16; ++k) {
            float4 a4 = *(const float4*)&As[k][ty << 2];
            float4 b4 = *(const float4*)&Bs[k][tx << 2];
            float aa[4] = {a4.x, a4.y, a4.z, a4.w};
            float bb[4] = {b4.x, b4.y, b4.z, b4.w};
#pragma unroll
            for (int i = 0; i < 4; ++i)
#pragma unroll
                for (int j = 0; j < 4; ++j)
                    acc[i][j] = fmaf(aa[i], bb[j], acc[i][j]);
        }
        __syncthreads();
    }

    float bj[4] = {0.f, 0.f, 0.f, 0.f};
    if (HB) {
#pragma unroll
        for (int j = 0; j < 4; ++j) bj[j] = bias[colBase + (tx << 2) + j];
    }
#pragma unroll
    for (int i = 0; i < 4; ++i) {
        float4 o;
        float* op = (float*)&o;
#pragma unroll
        for (int j = 0; j < 4; ++j) {
            float v = acc[i][j] + bj[j];
            if (EPI == 1) v = gelu_f(v);
            op[j] = v;
        }
        *(float4*)(C + (size_t)(rowBase + (ty << 2) + i) * M + colBase + (tx << 2)) = o;
    }
}

// -------- LayerNorm in-place over rows of 512 --------
__global__ __launch_bounds__(256) void ln_k(float* __restrict__ X,
                                            const float* __restrict__ g,
                                            const float* __restrict__ b)
{
    const int row = blockIdx.x, tid = threadIdx.x;
    float* x = X + (size_t)row * MD_;
    float v0 = x[tid], v1 = x[tid + 256];
    float s = v0 + v1, q = v0 * v0 + v1 * v1;
#pragma unroll
    for (int off = 32; off > 0; off >>= 1) {
        s += __shfl_down(s, off);
        q += __shfl_down(q, off);
    }
    __shared__ float redS[4], redQ[4];
    __shared__ float s_mean, s_rstd;
    const int lane = tid & 63, w = tid >> 6;
    if (lane == 0) { redS[w] = s; redQ[w] = q; }
    __syncthreads();
    if (tid == 0) {
        float S = redS[0] + redS[1] + redS[2] + redS[3];
        float Q = redQ[0] + redQ[1] + redQ[2] + redQ[3];
        float m = S * (1.f / 512.f);
        float var = Q * (1.f / 512.f) - m * m;
        s_mean = m; s_rstd = rsqrtf(var + 1e-5f);
    }
    __syncthreads();
    const float m = s_mean, rs = s_rstd;
    x[tid]       = (v0 - m) * rs * g[tid]       + b[tid];
    x[tid + 256] = (v1 - m) * rs * g[tid + 256] + b[tid + 256];
}

// -------- surprise + write-input: inputs = lr * mean((pred-v)^2) * v --------
__global__ __launch_bounds__(256) void surprise_k(const float* __restrict__ pred,
                                                  const float* __restrict__ v,
                                                  const float* __restrict__ lr_p,
                                                  float* __restrict__ out)
{
    const int row = blockIdx.x, tid = threadIdx.x;
    const float* pp = pred + (size_t)row * MD_;
    const float* vp = v + (size_t)row * MD_;
    float p0 = pp[tid], p1 = pp[tid + 256];
    float v0 = vp[tid], v1 = vp[tid + 256];
    float d0 = p0 - v0, d1 = p1 - v1;
    float q = d0 * d0 + d1 * d1;
#pragma unroll
    for (int off = 32; off > 0; off >>= 1) q += __shfl_down(q, off);
    __shared__ float redQ[4];
    __shared__ float s_coef;
    const int lane = tid & 63, w = tid >> 6;
    if (lane == 0) redQ[w] = q;
    __syncthreads();
    if (tid == 0) {
        float Q = redQ[0] + redQ[1] + redQ[2] + redQ[3];
        s_coef = lr_p[0] * (Q * (1.f / 512.f));
    }
    __syncthreads();
    const float c = s_coef;
    out[(size_t)row * MD_ + tid]       = c * v0;
    out[(size_t)row * MD_ + tid + 256] = c * v1;
}

// -------- scan pass 1: local chunk scan + carry-out --------
__global__ __launch_bounds__(256) void scan1_k(const float* __restrict__ in,
                                               const float* __restrict__ ff,
                                               float* __restrict__ loc,
                                               float* __restrict__ carry)
{
    const int idx = blockIdx.x * blockDim.x + threadIdx.x;  // B*NCH*MD
    const int d = idx & (MD_ - 1);
    const int c = (idx >> 9) & (NCH - 1);
    const int b = idx >> 14;
    const float g = gate_from_ff(ff);
    const float* p = in + ((size_t)(b * S_ + c * CHUNK)) * MD_ + d;
    float* q = loc + ((size_t)(b * S_ + c * CHUNK)) * MD_ + d;
    float s = 0.f;
#pragma unroll 4
    for (int t = 0; t < CHUNK; ++t) {
        s = fmaf(g, s, p[(size_t)t * MD_]);
        q[(size_t)t * MD_] = s;
    }
    carry[((size_t)b * NCH + c) * MD_ + d] = s;
}

// -------- scan pass 2: chunk-carry prefix (incoming state per chunk) --------
__global__ __launch_bounds__(256) void scan2_k(const float* __restrict__ carry,
                                               const float* __restrict__ ff,
                                               float* __restrict__ Sin)
{
    const int idx = blockIdx.x * blockDim.x + threadIdx.x;  // B*MD
    const int d = idx & (MD_ - 1);
    const int b = idx >> 9;
    const float g = gate_from_ff(ff);
    const float gL = powf(g, (float)CHUNK);
    float p = 0.f;
    for (int c = 0; c < NCH; ++c) {
        Sin[((size_t)b * NCH + c) * MD_ + d] = p;
        p = carry[((size_t)b * NCH + c) * MD_ + d] + gL * p;
    }
}

// -------- scan pass 3: add g^(tl+1) * incoming-state --------
__global__ __launch_bounds__(256) void scan3_k(float* __restrict__ loc,
                                               const float* __restrict__ Sin,
                                               const float* __restrict__ ff)
{
    const size_t idx = (size_t)blockIdx.x * blockDim.x + threadIdx.x;  // NTOK*MD
    const int d = (int)(idx & (MD_ - 1));
    const int t = (int)((idx >> 9) & (S_ - 1));
    const int b = (int)(idx >> 21);
    const int c = t >> 7, tl = t & (CHUNK - 1);
    const float g = gate_from_ff(ff);
    const float f = powf(g, (float)(tl + 1));
    loc[idx] += f * Sin[((size_t)b * NCH + c) * MD_ + d];
}

extern "C" void kernel_launch(void* const* d_in, const int* in_sizes, int n_in,
                              void* d_out, int out_size, void* d_ws, size_t ws_size,
                              hipStream_t stream) {
    const float* x   = (const float*)d_in[0];
    const float* Wd  = (const float*)d_in[1];
    const float* bd  = (const float*)d_in[2];
    const float* Wu  = (const float*)d_in[3];
    const float* bu  = (const float*)d_in[4];
    const float* Wq  = (const float*)d_in[5];
    const float* bq  = (const float*)d_in[6];
    const float* Wk  = (const float*)d_in[7];
    const float* bk  = (const float*)d_in[8];
    const float* Wv  = (const float*)d_in[9];
    const float* bv  = (const float*)d_in[10];
    const float* qg  = (const float*)d_in[11];
    const float* qb  = (const float*)d_in[12];
    const float* kg  = (const float*)d_in[13];
    const float* kb  = (const float*)d_in[14];
    const float* W0  = (const float*)d_in[15];
    const float* W1  = (const float*)d_in[16];
    const float* lr  = (const float*)d_in[17];
    const float* ff  = (const float*)d_in[18];
    float* out = (float*)d_out;

    const size_t NBUF = (size_t)NTOK * MD_;       // 8.39M floats
    float* bufA  = (float*)d_ws;                  // h -> aq -> ak -> inputs
    float* bufB  = bufA + NBUF;                   // qpre/q -> retrieved
    float* bufC  = bufB + NBUF;                   // kpre/k -> pred -> scanned
    float* bufD  = bufC + NBUF;                   // v
    float* carry = bufD + NBUF;                   // B*NCH*MD
    float* Sin   = carry + (size_t)B_ * NCH * MD_;

    dim3 blk(256);
    dim3 gridMD(MD_ / 64, NTOK / 64);
    dim3 gridD(D_ / 64, NTOK / 64);

    // h = x @ Wd + bd
    gemm_f32_k<0,1,0><<<gridMD, blk, 0, stream>>>(x, nullptr, Wd, bd, bufA, NTOK, D_, MD_);
    // qpre/kpre/v
    gemm_f32_k<0,1,0><<<gridMD, blk, 0, stream>>>(bufA, nullptr, Wq, bq, bufB, NTOK, MD_, MD_);
    gemm_f32_k<0,1,0><<<gridMD, blk, 0, stream>>>(bufA, nullptr, Wk, bk, bufC, NTOK, MD_, MD_);
    gemm_f32_k<0,1,0><<<gridMD, blk, 0, stream>>>(bufA, nullptr, Wv, bv, bufD, NTOK, MD_, MD_);
    // q = LN(qpre), k = LN(kpre)   (in place)
    ln_k<<<NTOK, 256, 0, stream>>>(bufB, qg, qb);
    ln_k<<<NTOK, 256, 0, stream>>>(bufC, kg, kb);
    // aq = gelu(q @ W0) -> bufA (h dead)
    gemm_f32_k<1,0,0><<<gridMD, blk, 0, stream>>>(bufB, nullptr, W0, nullptr, bufA, NTOK, MD_, MD_);
    // retrieved = aq @ W1 -> bufB (q dead)
    gemm_f32_k<0,0,0><<<gridMD, blk, 0, stream>>>(bufA, nullptr, W1, nullptr, bufB, NTOK, MD_, MD_);
    // ak = gelu(k @ W0) -> bufA (aq dead)
    gemm_f32_k<1,0,0><<<gridMD, blk, 0, stream>>>(bufC, nullptr, W0, nullptr, bufA, NTOK, MD_, MD_);
    // pred = ak @ W1 -> bufC (k dead)
    gemm_f32_k<0,0,0><<<gridMD, blk, 0, stream>>>(bufA, nullptr, W1, nullptr, bufC, NTOK, MD_, MD_);
    // inputs = lr * mean((pred-v)^2) * v -> bufA (ak dead)
    surprise_k<<<NTOK, 256, 0, stream>>>(bufC, bufD, lr, bufA);
    // scanned: 3-pass chunked linear scan -> bufC (pred dead)
    scan1_k<<<(B_ * NCH * MD_) / 256, 256, 0, stream>>>(bufA, ff, bufC, carry);
    scan2_k<<<(B_ * MD_) / 256, 256, 0, stream>>>(carry, ff, Sin);
    scan3_k<<<(NTOK * MD_) / 256, 256, 0, stream>>>(bufC, Sin, ff);
    // out = (retrieved + scanned) @ Wu + bu
    gemm_f32_k<0,1,1><<<gridD, blk, 0, stream>>>(bufB, bufC, Wu, bu, out, NTOK, MD_, D_);
}

// Round 2
// 304.460 us; speedup vs baseline: 4.5364x; 4.5364x over previous
//
#include <hip/hip_runtime.h>
#include <hip/hip_bf16.h>
#include <math.h>

#define B_    4
#define S_    4096
#define DD    1024
#define MD    512
#define NTOK  16384
#define CHUNK 128
#define NCH   32

typedef unsigned short u16;
typedef __attribute__((ext_vector_type(8))) short short8;
typedef __attribute__((ext_vector_type(4))) float f32x4;

__device__ __forceinline__ float bf2f(u16 u) {
    unsigned int x = ((unsigned int)u) << 16;
    return __builtin_bit_cast(float, x);
}
__device__ __forceinline__ u16 f2bf(float f) {
    unsigned int x = __builtin_bit_cast(unsigned int, f);
    unsigned int lsb = (x >> 16) & 1u;
    x += 0x7fffu + lsb;           // round-to-nearest-even
    return (u16)(x >> 16);
}
__device__ __forceinline__ float gelu_f(float x) {
    float x3 = x * x * x;
    return 0.5f * x * (1.0f + tanhf(0.7978845608028654f * (x + 0.044715f * x3)));
}
__device__ __forceinline__ float gate_from_ff(const float* ff) {
    return 1.0f - 1.0f / (1.0f + expf(-ff[0]));
}

#define GLDS(gp, lp) __builtin_amdgcn_global_load_lds( \
    (const __attribute__((address_space(1))) void*)(gp), \
    (__attribute__((address_space(3))) void*)(lp), 16, 0, 0)

// ---------------- bf16 MFMA GEMM (m97 structure) ----------------
// C[N][M] = epi(A[N][K] @ BT[M][K]^T + bias), all bf16 inputs, f32 accum.
// 128x128 tile, BK=32, 4 waves, 64x64 per wave, 16x16x32 MFMA.
template<int EPI, int HB, int OUTBF>
__global__ __launch_bounds__(256) void gemm_bf16_k(
    const u16* __restrict__ A, const u16* __restrict__ BT,
    const float* __restrict__ bias, void* __restrict__ C,
    int N, int K, int M)
{
    __shared__ __align__(16) u16 Al[2][128 * 32];
    __shared__ __align__(16) u16 Bl[2][128 * 32];
    const int tid = threadIdx.x;
    const int w = tid >> 6, l = tid & 63;
    const int rowBase = blockIdx.y * 128, colBase = blockIdx.x * 128;
    const int wm = (w >> 1) * 64, wn = (w & 1) * 64;

    // staging: wave w fills segments {w, w+4}; segment s = 16 rows x 64B = 1KB
    const int srow = l >> 2;             // 0..15
    const int skoff = (l & 3) * 8;       // k-element offset within row
    const u16* Ag0 = A  + (size_t)(rowBase + w * 16 + srow) * K + skoff;
    const u16* Ag1 = A  + (size_t)(rowBase + (w + 4) * 16 + srow) * K + skoff;
    const u16* Bg0 = BT + (size_t)(colBase + w * 16 + srow) * K + skoff;
    const u16* Bg1 = BT + (size_t)(colBase + (w + 4) * 16 + srow) * K + skoff;

    f32x4 acc[4][4];
#pragma unroll
    for (int i = 0; i < 4; ++i)
#pragma unroll
        for (int j = 0; j < 4; ++j) acc[i][j] = (f32x4){0.f, 0.f, 0.f, 0.f};

    const int KT = K >> 5;
    // prologue: stage tile 0 into buffer 0
    GLDS(Ag0, &Al[0][(w * 16) * 32]);
    GLDS(Ag1, &Al[0][((w + 4) * 16) * 32]);
    GLDS(Bg0, &Bl[0][(w * 16) * 32]);
    GLDS(Bg1, &Bl[0][((w + 4) * 16) * 32]);
    __syncthreads();

    const int lr = l & 15;
    const int goff = (l >> 4) * 8;       // k-chunk within lane-group
    int cur = 0;
    for (int kt = 0; kt < KT; ++kt) {
        if (kt + 1 < KT) {
            const size_t ko = (size_t)(kt + 1) << 5;
            GLDS(Ag0 + ko, &Al[cur ^ 1][(w * 16) * 32]);
            GLDS(Ag1 + ko, &Al[cur ^ 1][((w + 4) * 16) * 32]);
            GLDS(Bg0 + ko, &Bl[cur ^ 1][(w * 16) * 32]);
            GLDS(Bg1 + ko, &Bl[cur ^ 1][((w + 4) * 16) * 32]);
        }
        short8 af[4], bfr[4];
#pragma unroll
        for (int m = 0; m < 4; ++m)
            af[m] = *(const short8*)&Al[cur][(wm + m * 16 + lr) * 32 + goff];
#pragma unroll
        for (int n = 0; n < 4; ++n)
            bfr[n] = *(const short8*)&Bl[cur][(wn + n * 16 + lr) * 32 + goff];
#pragma unroll
        for (int m = 0; m < 4; ++m)
#pragma unroll
            for (int n = 0; n < 4; ++n)
                acc[m][n] = __builtin_amdgcn_mfma_f32_16x16x32_bf16(af[m], bfr[n], acc[m][n], 0, 0, 0);
        __syncthreads();
        cur ^= 1;
    }

    // epilogue: D layout col=lane&15, row=(lane>>4)*4+reg
    const int g4 = (l >> 4) * 4;
#pragma unroll
    for (int n = 0; n < 4; ++n) {
        const int col = colBase + wn + n * 16 + lr;
        const float bj = HB ? bias[col] : 0.0f;
#pragma unroll
        for (int m = 0; m < 4; ++m) {
            const int row0 = rowBase + wm + m * 16 + g4;
#pragma unroll
            for (int q = 0; q < 4; ++q) {
                float vv = acc[m][n][q] + bj;
                if (EPI == 1) vv = gelu_f(vv);
                if (OUTBF) ((u16*)C)[(size_t)(row0 + q) * M + col] = f2bf(vv);
                else       ((float*)C)[(size_t)(row0 + q) * M + col] = vv;
            }
        }
    }
}

// ---------------- f32 -> bf16 bulk convert ----------------
__global__ __launch_bounds__(256) void cvt_bf16_k(const float* __restrict__ in,
                                                  u16* __restrict__ out, int n)
{
    size_t i = ((size_t)blockIdx.x * 256 + threadIdx.x) * 8;
    if (i + 8 > (size_t)n) return;
    float4 a = *(const float4*)(in + i);
    float4 b = *(const float4*)(in + i + 4);
    short8 o;
    o[0] = (short)f2bf(a.x); o[1] = (short)f2bf(a.y);
    o[2] = (short)f2bf(a.z); o[3] = (short)f2bf(a.w);
    o[4] = (short)f2bf(b.x); o[5] = (short)f2bf(b.y);
    o[6] = (short)f2bf(b.z); o[7] = (short)f2bf(b.w);
    *(short8*)(out + i) = o;
}

// ---------------- weight transpose+convert: W[K][M] f32 -> WT[M][K] bf16 ----------------
__global__ __launch_bounds__(256) void wtrans_k(const float* __restrict__ W,
                                                u16* __restrict__ WT, int K, int M)
{
    __shared__ float t[32][33];
    const int tx = threadIdx.x, ty = threadIdx.y;  // (32,8)
    const int m0 = blockIdx.x * 32, k0 = blockIdx.y * 32;
#pragma unroll
    for (int i = 0; i < 4; ++i)
        t[ty + i * 8][tx] = W[(size_t)(k0 + ty + i * 8) * M + m0 + tx];
    __syncthreads();
#pragma unroll
    for (int i = 0; i < 4; ++i)
        WT[(size_t)(m0 + ty + i * 8) * K + k0 + tx] = f2bf(t[tx][ty + i * 8]);
}

__global__ __launch_bounds__(256) void wtrans5_k(
    const float* __restrict__ Wa, const float* __restrict__ Wb,
    const float* __restrict__ Wc, const float* __restrict__ Wd_,
    const float* __restrict__ We,
    u16* __restrict__ Ta, u16* __restrict__ Tb, u16* __restrict__ Tc,
    u16* __restrict__ Td, u16* __restrict__ Te)
{
    __shared__ float t[32][33];
    const float* W; u16* T;
    switch (blockIdx.z) {
        case 0: W = Wa; T = Ta; break;
        case 1: W = Wb; T = Tb; break;
        case 2: W = Wc; T = Tc; break;
        case 3: W = Wd_; T = Td; break;
        default: W = We; T = Te; break;
    }
    const int tx = threadIdx.x, ty = threadIdx.y;
    const int m0 = blockIdx.x * 32, k0 = blockIdx.y * 32;
#pragma unroll
    for (int i = 0; i < 4; ++i)
        t[ty + i * 8][tx] = W[(size_t)(k0 + ty + i * 8) * 512 + m0 + tx];
    __syncthreads();
#pragma unroll
    for (int i = 0; i < 4; ++i)
        T[(size_t)(m0 + ty + i * 8) * 512 + k0 + tx] = f2bf(t[tx][ty + i * 8]);
}

// ---------------- LayerNorm: f32 in -> bf16 out, rows of 512 ----------------
__global__ __launch_bounds__(256) void ln_k(const float* __restrict__ X,
                                            u16* __restrict__ Y,
                                            const float* __restrict__ g,
                                            const float* __restrict__ b)
{
    const int row = blockIdx.x, tid = threadIdx.x;
    const float* x = X + (size_t)row * MD;
    float v0 = x[tid], v1 = x[tid + 256];
    float s = v0 + v1, q = v0 * v0 + v1 * v1;
#pragma unroll
    for (int off = 32; off > 0; off >>= 1) {
        s += __shfl_down(s, off);
        q += __shfl_down(q, off);
    }
    __shared__ float redS[4], redQ[4];
    __shared__ float s_mean, s_rstd;
    const int lane = tid & 63, w = tid >> 6;
    if (lane == 0) { redS[w] = s; redQ[w] = q; }
    __syncthreads();
    if (tid == 0) {
        float S = redS[0] + redS[1] + redS[2] + redS[3];
        float Q = redQ[0] + redQ[1] + redQ[2] + redQ[3];
        float m = S * (1.f / 512.f);
        float var = Q * (1.f / 512.f) - m * m;
        s_mean = m; s_rstd = rsqrtf(var + 1e-5f);
    }
    __syncthreads();
    const float m = s_mean, rs = s_rstd;
    u16* y = Y + (size_t)row * MD;
    y[tid]       = f2bf((v0 - m) * rs * g[tid]       + b[tid]);
    y[tid + 256] = f2bf((v1 - m) * rs * g[tid + 256] + b[tid + 256]);
}

// ---------------- surprise: inputs = lr * mean((pred-v)^2) * v, in-place on v ----------------
__global__ __launch_bounds__(256) void surprise_k(const u16* __restrict__ pred,
                                                  u16* __restrict__ v,
                                                  const float* __restrict__ lr_p)
{
    const int row = blockIdx.x, tid = threadIdx.x;
    const u16* pp = pred + (size_t)row * MD;
    u16* vp = v + (size_t)row * MD;
    float p0 = bf2f(pp[tid]), p1 = bf2f(pp[tid + 256]);
    float v0 = bf2f(vp[tid]), v1 = bf2f(vp[tid + 256]);
    float d0 = p0 - v0, d1 = p1 - v1;
    float q = d0 * d0 + d1 * d1;
#pragma unroll
    for (int off = 32; off > 0; off >>= 1) q += __shfl_down(q, off);
    __shared__ float redQ[4];
    __shared__ float s_coef;
    const int lane = tid & 63, w = tid >> 6;
    if (lane == 0) redQ[w] = q;
    __syncthreads();
    if (tid == 0) {
        float Q = redQ[0] + redQ[1] + redQ[2] + redQ[3];
        s_coef = lr_p[0] * (Q * (1.f / 512.f));
    }
    __syncthreads();
    const float c = s_coef;
    vp[tid]       = f2bf(c * v0);
    vp[tid + 256] = f2bf(c * v1);
}

// ---------------- chunked linear scan (gate is a scalar constant) ----------------
__global__ __launch_bounds__(256) void scan1_k(u16* __restrict__ io,
                                               const float* __restrict__ ff,
                                               float* __restrict__ carry)
{
    const int idx = blockIdx.x * blockDim.x + threadIdx.x;  // B*NCH*MD
    const int d = idx & (MD - 1);
    const int c = (idx >> 9) & (NCH - 1);
    const int b = idx >> 14;
    const float g = gate_from_ff(ff);
    u16* p = io + ((size_t)(b * S_ + c * CHUNK)) * MD + d;
    float s = 0.f;
#pragma unroll 4
    for (int t = 0; t < CHUNK; ++t) {
        s = fmaf(g, s, bf2f(p[(size_t)t * MD]));
        p[(size_t)t * MD] = f2bf(s);
    }
    carry[((size_t)b * NCH + c) * MD + d] = s;
}

__global__ __launch_bounds__(256) void scan2_k(const float* __restrict__ carry,
                                               const float* __restrict__ ff,
                                               float* __restrict__ Sin)
{
    const int idx = blockIdx.x * blockDim.x + threadIdx.x;  // B*MD
    const int d = idx & (MD - 1);
    const int b = idx >> 9;
    const float g = gate_from_ff(ff);
    const float gL = powf(g, (float)CHUNK);
    float p = 0.f;
    for (int c = 0; c < NCH; ++c) {
        Sin[((size_t)b * NCH + c) * MD + d] = p;
        p = carry[((size_t)b * NCH + c) * MD + d] + gL * p;
    }
}

// fin = bf16( loc + g^(tl+1)*Sin + retrieved )
__global__ __launch_bounds__(256) void scan3_k(const u16* __restrict__ loc,
                                               const float* __restrict__ Sin,
                                               const float* __restrict__ retr,
                                               const float* __restrict__ ff,
                                               u16* __restrict__ fin)
{
    const size_t idx = (size_t)blockIdx.x * blockDim.x + threadIdx.x;  // NTOK*MD
    const int d = (int)(idx & (MD - 1));
    const int t = (int)((idx >> 9) & (S_ - 1));
    const int b = (int)(idx >> 21);
    const int c = t >> 7, tl = t & (CHUNK - 1);
    const float g = gate_from_ff(ff);
    const float f = exp2f((float)(tl + 1) * log2f(g));
    float v = bf2f(loc[idx]) + f * Sin[((size_t)b * NCH + c) * MD + d] + retr[idx];
    fin[idx] = f2bf(v);
}

extern "C" void kernel_launch(void* const* d_in, const int* in_sizes, int n_in,
                              void* d_out, int out_size, void* d_ws, size_t ws_size,
                              hipStream_t stream) {
    const float* x   = (const float*)d_in[0];
    const float* Wd  = (const float*)d_in[1];
    const float* bd  = (const float*)d_in[2];
    const float* Wu  = (const float*)d_in[3];
    const float* bu  = (const float*)d_in[4];
    const float* Wq  = (const float*)d_in[5];
    const float* bq  = (const float*)d_in[6];
    const float* Wk  = (const float*)d_in[7];
    const float* bk  = (const float*)d_in[8];
    const float* Wv  = (const float*)d_in[9];
    const float* bv  = (const float*)d_in[10];
    const float* qg  = (const float*)d_in[11];
    const float* qb  = (const float*)d_in[12];
    const float* kg  = (const float*)d_in[13];
    const float* kb  = (const float*)d_in[14];
    const float* W0  = (const float*)d_in[15];
    const float* W1  = (const float*)d_in[16];
    const float* lr  = (const float*)d_in[17];
    const float* ff  = (const float*)d_in[18];
    float* out = (float*)d_out;

    // ---- workspace layout (~103 MB) ----
    u16* wdT = (u16*)d_ws;                      // [512][1024]
    u16* wqT = wdT + 512 * 1024;                // [512][512]
    u16* wkT = wqT + 512 * 512;
    u16* wvT = wkT + 512 * 512;
    u16* w0T = wvT + 512 * 512;
    u16* w1T = w0T + 512 * 512;
    u16* wuT = w1T + 512 * 512;                 // [1024][512]
    u16* xb  = wuT + 1024 * 512;                // [16384][1024] bf16 (32MB)
    u16* b1  = xb;                              // alias after G1: [16384][512]
    u16* b2  = xb + (size_t)NTOK * MD;          // alias: second half
    u16* hb  = xb + (size_t)NTOK * DD;          // [16384][512] bf16 (16MB)
    u16* b3  = hb;                              // alias after G4
    float* P   = (float*)(hb + (size_t)NTOK * MD);   // [16384][512] f32 (33.5MB)
    u16* VB    = (u16*)(P + (size_t)NTOK * MD);      // [16384][512] bf16 (16MB)
    float* carry = (float*)(VB + (size_t)NTOK * MD); // [B][NCH][MD]
    float* Sin   = carry + B_ * NCH * MD;

    dim3 blk(256);
    dim3 t32(32, 8);

    // convert inputs
    cvt_bf16_k<<<(NTOK * DD) / (256 * 8), blk, 0, stream>>>(x, xb, NTOK * DD);
    wtrans_k<<<dim3(512 / 32, 1024 / 32), t32, 0, stream>>>(Wd, wdT, 1024, 512);
    wtrans5_k<<<dim3(16, 16, 5), t32, 0, stream>>>(Wq, Wk, Wv, W0, W1,
                                                   wqT, wkT, wvT, w0T, w1T);
    wtrans_k<<<dim3(1024 / 32, 512 / 32), t32, 0, stream>>>(Wu, wuT, 512, 1024);

    // G1: h = x @ Wd + bd  -> hb (bf16)
    gemm_bf16_k<0, 1, 1><<<dim3(4, 128), blk, 0, stream>>>(xb, wdT, bd, hb, NTOK, 1024, 512);
    // G2: qpre -> P (f32); LN -> b1 (bf16)
    gemm_bf16_k<0, 1, 0><<<dim3(4, 128), blk, 0, stream>>>(hb, wqT, bq, P, NTOK, 512, 512);
    ln_k<<<NTOK, blk, 0, stream>>>(P, b1, qg, qb);
    // G3: kpre -> P; LN -> b2
    gemm_bf16_k<0, 1, 0><<<dim3(4, 128), blk, 0, stream>>>(hb, wkT, bk, P, NTOK, 512, 512);
    ln_k<<<NTOK, blk, 0, stream>>>(P, b2, kg, kb);
    // G4: v -> VB (bf16)
    gemm_bf16_k<0, 1, 1><<<dim3(4, 128), blk, 0, stream>>>(hb, wvT, bv, VB, NTOK, 512, 512);
    // G5: aq = gelu(q @ W0) -> b3 (bf16)
    gemm_bf16_k<1, 0, 1><<<dim3(4, 128), blk, 0, stream>>>(b1, w0T, nullptr, b3, NTOK, 512, 512);
    // G6: retrieved = aq @ W1 -> P (f32)
    gemm_bf16_k<0, 0, 0><<<dim3(4, 128), blk, 0, stream>>>(b3, w1T, nullptr, P, NTOK, 512, 512);
    // G7: ak = gelu(k @ W0) -> b3
    gemm_bf16_k<1, 0, 1><<<dim3(4, 128), blk, 0, stream>>>(b2, w0T, nullptr, b3, NTOK, 512, 512);
    // G8: pred = ak @ W1 -> b1 (bf16)
    gemm_bf16_k<0, 0, 1><<<dim3(4, 128), blk, 0, stream>>>(b3, w1T, nullptr, b1, NTOK, 512, 512);
    // surprise-weighted write inputs (in-place on VB)
    surprise_k<<<NTOK, blk, 0, stream>>>(b1, VB, lr);
    // chunked scan
    scan1_k<<<(B_ * NCH * MD) / 256, blk, 0, stream>>>(VB, ff, carry);
    scan2_k<<<(B_ * MD) / 256, blk, 0, stream>>>(carry, ff, Sin);
    scan3_k<<<(NTOK * MD) / 256, blk, 0, stream>>>(VB, Sin, P, ff, b2);
    // G9: out = fin @ Wu + bu -> d_out (f32)
    gemm_bf16_k<0, 1, 0><<<dim3(8, 128), blk, 0, stream>>>(b2, wuT, bu, out, NTOK, 512, 1024);
}